// Round 7
// baseline (307.430 us; speedup 1.0000x reference)
//
#include <hip/hip_runtime.h>
#include <hip/hip_bf16.h>

#define B_    32
#define SDEC  128
#define SENC  128
#define V_    32000
#define E_    200
#define H_    128
#define G3    384   // 3*H

typedef __attribute__((ext_vector_type(8))) short bf16x8;
typedef __attribute__((ext_vector_type(4))) float f32x4;
typedef __attribute__((ext_vector_type(2))) float f32x2;

#define GLOBAL_AS __attribute__((address_space(1)))
#define LDS_AS    __attribute__((address_space(3)))

__device__ __forceinline__ float fast_sigmoid(float x) {
  return 1.f / (1.f + __expf(-x));
}
__device__ __forceinline__ float fast_tanh(float x) {
  float e2 = __expf(2.f * x);
  return 1.f - 2.f / (e2 + 1.f);
}
// butterfly sum over each aligned 4-lane quad, pure VALU (DPP quad_perm)
__device__ __forceinline__ float quad_reduce(float x) {
  int i = __builtin_bit_cast(int, x);
  int a = __builtin_amdgcn_mov_dpp(i, 0xB1, 0xF, 0xF, true);  // xor 1
  float s = x + __builtin_bit_cast(float, a);
  int j = __builtin_bit_cast(int, s);
  int c = __builtin_amdgcn_mov_dpp(j, 0x4E, 0xF, 0xF, true);  // xor 2
  return s + __builtin_bit_cast(float, c);
}

// ---------------------------------------------------------------------------
// Kernel 1: x = emb[seq]; xg = x @ w_ih^T + b_ih   -> xg [4096][384] f32
// 128 threads, 3 gate-cols each: LDS broadcast instrs cut 33% (was LDS-bound).
// ---------------------------------------------------------------------------
__global__ __launch_bounds__(128) void k_embed_proj(
    const int* __restrict__ seq, const float* __restrict__ emb,
    const float* __restrict__ w_ih, const float* __restrict__ b_ih,
    float* __restrict__ xg) {
  __shared__ __align__(16) float xs[16][E_];
  __shared__ int sidx[16];
  const int r0 = blockIdx.x * 16;
  const int t = threadIdx.x;
  if (t < 16) sidx[t] = seq[r0 + t];
  __syncthreads();
  for (int i = t; i < 800; i += 128) {
    int r = i / 50, c = i - r * 50;
    *(float4*)&xs[r][c * 4] =
        *(const float4*)(emb + (size_t)sidx[r] * E_ + c * 4);
  }
  __syncthreads();
  const int g0 = t, g1 = t + 128, g2 = t + 256;
  float a0[16], a1[16], a2[16];
#pragma unroll
  for (int r = 0; r < 16; r++) { a0[r] = 0.f; a1[r] = 0.f; a2[r] = 0.f; }
  const float* w0 = w_ih + (size_t)g0 * E_;
  const float* w1 = w_ih + (size_t)g1 * E_;
  const float* w2 = w_ih + (size_t)g2 * E_;
  for (int k = 0; k < E_; k += 4) {
    float4 wv0 = *(const float4*)(w0 + k);
    float4 wv1 = *(const float4*)(w1 + k);
    float4 wv2 = *(const float4*)(w2 + k);
#pragma unroll
    for (int r = 0; r < 16; r++) {
      float4 xv = *(const float4*)&xs[r][k];
      a0[r] += wv0.x * xv.x + wv0.y * xv.y + wv0.z * xv.z + wv0.w * xv.w;
      a1[r] += wv1.x * xv.x + wv1.y * xv.y + wv1.z * xv.z + wv1.w * xv.w;
      a2[r] += wv2.x * xv.x + wv2.y * xv.y + wv2.z * xv.z + wv2.w * xv.w;
    }
  }
  const float b0 = b_ih[g0], b1 = b_ih[g1], b2 = b_ih[g2];
#pragma unroll
  for (int r = 0; r < 16; r++) {
    xg[(size_t)(r0 + r) * G3 + g0] = a0[r] + b0;
    xg[(size_t)(r0 + r) * G3 + g1] = a1[r] + b1;
    xg[(size_t)(r0 + r) * G3 + g2] = a2[r] + b2;
  }
}

// ---------------------------------------------------------------------------
// Kernel 2: blocks 0..31  : GRU scan + fused MFMA attention (one batch each)
//           blocks 32..531: w_out f32->bf16, 4 ILP chunks each
// ---------------------------------------------------------------------------
__global__ __launch_bounds__(512) void k_gru_attn_cvt(
    const float* __restrict__ xg, const float* __restrict__ h0,
    const float* __restrict__ w_hh, const float* __restrict__ b_hh,
    const float* __restrict__ hs, __hip_bfloat16* __restrict__ cat_bf,
    float* __restrict__ state_out, float* __restrict__ attw_out,
    const float* __restrict__ w_out, __hip_bfloat16* __restrict__ wout_bf) {
  if (blockIdx.x >= 32) {
    const int base = (blockIdx.x - 32) * 4;
#pragma unroll
    for (int j = 0; j < 4; j++) {
      int idx = ((base + j) * 512 + threadIdx.x) * 8;
      float4 a = *(const float4*)(w_out + idx);
      float4 c = *(const float4*)(w_out + idx + 4);
      union { __hip_bfloat16 h[8]; uint4 v; } p;
      p.h[0] = __float2bfloat16(a.x); p.h[1] = __float2bfloat16(a.y);
      p.h[2] = __float2bfloat16(a.z); p.h[3] = __float2bfloat16(a.w);
      p.h[4] = __float2bfloat16(c.x); p.h[5] = __float2bfloat16(c.y);
      p.h[6] = __float2bfloat16(c.z); p.h[7] = __float2bfloat16(c.w);
      *(uint4*)(wout_bf + idx) = p.v;
    }
    return;
  }

  __shared__ __hip_bfloat16 ctb[128][128];  // GRU out (scan) -> P (phase 4)
  __shared__ __hip_bfloat16 hsb[128][128];  // hs rows,  chunk c ^ (e&7)
  __shared__ __hip_bfloat16 hsT[128][128];  // hs^T, col' = (e + 8*(h&15))&127
  __shared__ __align__(16) float hp[2][H_];

  const int b = blockIdx.x;
  const int t = threadIdx.x;
  const int hh = t >> 2;   // owned h element
  const int sub = t & 3;   // k-quarter

  float wr_[32], wz_[32], wn_[32];
#pragma unroll
  for (int m = 0; m < 8; m++) {
    int c = (m + sub * 2) & 7;
    int kb = sub * 32 + c * 4;
    *(float4*)&wr_[m * 4] = *(const float4*)(w_hh + (size_t)hh * H_ + kb);
    *(float4*)&wz_[m * 4] = *(const float4*)(w_hh + (size_t)(128 + hh) * H_ + kb);
    *(float4*)&wn_[m * 4] = *(const float4*)(w_hh + (size_t)(256 + hh) * H_ + kb);
  }

  const float* xgb = xg + (size_t)b * SDEC * G3;
  const float br = b_hh[hh], bz = b_hh[128 + hh], bn = b_hh[256 + hh];
  float cxr = xgb[hh], cxz = xgb[128 + hh], cxn = xgb[256 + hh];
  if (t < H_) hp[0][t] = h0[b * H_ + t];
  __hip_bfloat16* catbfb = cat_bf + (size_t)b * SDEC * 256;

  asm volatile("s_waitcnt lgkmcnt(0)" ::: "memory");
  __builtin_amdgcn_s_barrier();
  asm volatile("" ::: "memory");

  int cur = 0;
  for (int s = 0; s < SDEC; s++) {
    float nxr = 0.f, nxz = 0.f, nxn = 0.f;
    if (s + 1 < SDEC) {
      const float* xp = xgb + (size_t)(s + 1) * G3;
      nxr = xp[hh]; nxz = xp[128 + hh]; nxn = xp[256 + hh];
    }
    f32x2 sr2 = {0.f, 0.f}, sz2 = {0.f, 0.f}, sn2 = {0.f, 0.f};
#pragma unroll
    for (int m = 0; m < 8; m++) {
      int c = (m + sub * 2) & 7;
      float4 hv = *(const float4*)&hp[cur][sub * 32 + c * 4];
      f32x2 h01 = {hv.x, hv.y}, h23 = {hv.z, hv.w};
      const f32x2* w2r = (const f32x2*)&wr_[m * 4];
      const f32x2* w2z = (const f32x2*)&wz_[m * 4];
      const f32x2* w2n = (const f32x2*)&wn_[m * 4];
      sr2 += w2r[0] * h01; sr2 += w2r[1] * h23;
      sz2 += w2z[0] * h01; sz2 += w2z[1] * h23;
      sn2 += w2n[0] * h01; sn2 += w2n[1] * h23;
    }
    float sr = quad_reduce(sr2[0] + sr2[1]);
    float sz = quad_reduce(sz2[0] + sz2[1]);
    float sn = quad_reduce(sn2[0] + sn2[1]);

    float hold = hp[cur][hh];
    float r = fast_sigmoid(cxr + sr + br);
    float z = fast_sigmoid(cxz + sz + bz);
    float n = fast_tanh(cxn + r * (sn + bn));
    float hnew = (1.f - z) * n + z * hold;
    if (sub == 0) {
      __hip_bfloat16 hb = __float2bfloat16(hnew);
      hp[cur ^ 1][hh] = hnew;
      catbfb[(size_t)s * 256 + hh] = hb;
      ctb[s][((hh >> 3) ^ (s & 7)) * 8 + (hh & 7)] = hb;  // fragment layout
    }
    asm volatile("s_waitcnt lgkmcnt(0)" ::: "memory");
    __builtin_amdgcn_s_barrier();
    asm volatile("" ::: "memory");
    cur ^= 1;
    cxr = nxr; cxz = nxz; cxn = nxn;
  }

  // ================== fused attention (same block, batch b) ================
  const int w = t >> 6, l = t & 63;
  const int lr = l & 15, lk = l >> 4;
  const float* hsbase = hs + (size_t)b * SENC * H_;

  // stage hs (f32 -> bf16, swizzled rows) + final state
  for (int i = t; i < 2048; i += 512) {
    int e = i >> 4, c = i & 15;
    float4 v0 = *(const float4*)(hsbase + e * H_ + c * 8);
    float4 v1 = *(const float4*)(hsbase + e * H_ + c * 8 + 4);
    union { __hip_bfloat16 h[8]; uint4 u; } pk;
    pk.h[0] = __float2bfloat16(v0.x); pk.h[1] = __float2bfloat16(v0.y);
    pk.h[2] = __float2bfloat16(v0.z); pk.h[3] = __float2bfloat16(v0.w);
    pk.h[4] = __float2bfloat16(v1.x); pk.h[5] = __float2bfloat16(v1.y);
    pk.h[6] = __float2bfloat16(v1.z); pk.h[7] = __float2bfloat16(v1.w);
    *(uint4*)&hsb[e][((c ^ (e & 7)) * 8)] = pk.u;
  }
  if (t < H_) state_out[b * H_ + t] = hp[cur][t];
  __syncthreads();

  // build rotated hs^T from hsb
  for (int i = t; i < 2048; i += 512) {
    int c = i >> 7, e = i & 127;
    uint4 v = *(const uint4*)&hsb[e][((c ^ (e & 7)) * 8)];
    const __hip_bfloat16* hv = (const __hip_bfloat16*)&v;
#pragma unroll
    for (int u = 0; u < 8; u++) {
      int h = c * 8 + u;
      int col = (e + 8 * (h & 15)) & 127;
      hsT[h][col] = hv[u];
    }
  }
  // A-fragments (ct rows) into registers before ctb is overlaid by P
  const int d = w * 16 + lr;
  bf16x8 afrag[4];
#pragma unroll
  for (int kt = 0; kt < 4; kt++)
    afrag[kt] = *(const bf16x8*)&ctb[d][(((kt * 4 + lk) ^ (lr & 7)) * 8)];
  __syncthreads();  // hsT ready; all ctb reads complete

  // phase 2: scores S[d][e]
  f32x4 acc[8];
#pragma unroll
  for (int et = 0; et < 8; et++) acc[et] = (f32x4){0.f, 0.f, 0.f, 0.f};
#pragma unroll
  for (int et = 0; et < 8; et++) {
#pragma unroll
    for (int kt = 0; kt < 4; kt++) {
      bf16x8 bfrag =
          *(const bf16x8*)&hsb[et * 16 + lr][(((kt * 4 + lk) ^ (lr & 7)) * 8)];
      acc[et] =
          __builtin_amdgcn_mfma_f32_16x16x32_bf16(bfrag, afrag[kt], acc[et], 0, 0, 0);
    }
  }

  // phase 3: softmax over e, in-register
  float mx = -1e30f;
#pragma unroll
  for (int et = 0; et < 8; et++)
    mx = fmaxf(mx, fmaxf(fmaxf(acc[et][0], acc[et][1]),
                         fmaxf(acc[et][2], acc[et][3])));
  mx = fmaxf(mx, __shfl_xor(mx, 16));
  mx = fmaxf(mx, __shfl_xor(mx, 32));
  float sum = 0.f;
#pragma unroll
  for (int et = 0; et < 8; et++) {
    acc[et][0] = __expf(acc[et][0] - mx);
    acc[et][1] = __expf(acc[et][1] - mx);
    acc[et][2] = __expf(acc[et][2] - mx);
    acc[et][3] = __expf(acc[et][3] - mx);
    sum += acc[et][0] + acc[et][1] + acc[et][2] + acc[et][3];
  }
  sum += __shfl_xor(sum, 16);
  sum += __shfl_xor(sum, 32);
  const float inv = 1.f / sum;

  // write P (bf16, into ctb space) + attw (f32)
  __hip_bfloat16 (*plds)[128] = ctb;
  float* aw = attw_out + (size_t)b * SENC * SDEC + d;
#pragma unroll
  for (int et = 0; et < 8; et++) {
    acc[et][0] *= inv; acc[et][1] *= inv;
    acc[et][2] *= inv; acc[et][3] *= inv;
    union { __hip_bfloat16 h[4]; uint2 u; } pk4;
    pk4.h[0] = __float2bfloat16(acc[et][0]);
    pk4.h[1] = __float2bfloat16(acc[et][1]);
    pk4.h[2] = __float2bfloat16(acc[et][2]);
    pk4.h[3] = __float2bfloat16(acc[et][3]);
    *(uint2*)&plds[d][(((et * 2 + (lk >> 1)) ^ (lr & 7)) * 8 + 4 * (lk & 1))] =
        pk4.u;
    const int e0 = et * 16 + lk * 4;
#pragma unroll
    for (int j = 0; j < 4; j++)
      aw[(size_t)(e0 + j) * SDEC] = acc[et][j];
  }
  __syncthreads();

  // phase 4: context c[d][h] = P @ hs
  bf16x8 pfrag[4];
#pragma unroll
  for (int f = 0; f < 4; f++)
    pfrag[f] = *(const bf16x8*)&plds[d][(((f * 4 + lk) ^ (lr & 7)) * 8)];
#pragma unroll
  for (int ht = 0; ht < 8; ht++) {
    f32x4 a2 = (f32x4){0.f, 0.f, 0.f, 0.f};
#pragma unroll
    for (int kt = 0; kt < 4; kt++) {
      bf16x8 hfrag =
          *(const bf16x8*)&hsT[ht * 16 + lr][((kt * 32 + lk * 8 + 8 * lr) & 127)];
      a2 = __builtin_amdgcn_mfma_f32_16x16x32_bf16(hfrag, pfrag[kt], a2, 0, 0, 0);
    }
    union { __hip_bfloat16 h[4]; uint2 u; } pk4;
    pk4.h[0] = __float2bfloat16(a2[0]);
    pk4.h[1] = __float2bfloat16(a2[1]);
    pk4.h[2] = __float2bfloat16(a2[2]);
    pk4.h[3] = __float2bfloat16(a2[3]);
    *(uint2*)(cat_bf + (size_t)(b * SDEC + d) * 256 + 128 + ht * 16 + lk * 4) =
        pk4.u;
  }
}

// ---------------------------------------------------------------------------
// Kernel 4: logits = cat @ w_out^T + b_out
// NEW geometry: 256x256 tile, 2000 blocks, 8 waves (2Mx4N, each 128x64).
// Same proven pipeline: 3 buffers (3x32KB=96KB), single barrier + counted
// vmcnt(4) per K-step, 2-deep prefetch. Quarter-tile (64-row) epilogue.
// ---------------------------------------------------------------------------
__global__ __launch_bounds__(512, 2) void k_gemm_mfma(
    const __hip_bfloat16* __restrict__ A, const __hip_bfloat16* __restrict__ Bw,
    const float* __restrict__ b_out, float* __restrict__ C) {
  constexpr int K = 256, N = V_, Kt = 32;
  alignas(16) __shared__ char smem[98304];  // 96 KB
  __hip_bfloat16 (*As)[8192] = (__hip_bfloat16(*)[8192])smem;            // [3][256*32]
  __hip_bfloat16 (*Bs)[8192] = (__hip_bfloat16(*)[8192])(smem + 49152);  // [3][256*32]
  float* tr = (float*)smem;  // epilogue: [64][260] padded f32 quarter (66.5KB)

  const int tid = threadIdx.x;
  const int w = tid >> 6, l = tid & 63;
  const int wr = w >> 2, wc = w & 3;       // 2M x 4N waves, each 128x64
  const int lr = l & 15, lk = l >> 4;
  const int lq = l >> 2, lc = l & 3;       // staging lane -> (row-in-16, 16B chunk)

  // bijective XCD swizzle: 2000 = 8 x 250; m fastest within an XCD chunk
  const int bid = blockIdx.x;
  const int wgid = (bid & 7) * 250 + (bid >> 3);
  const int mt = wgid & 15;    // 0..15
  const int nt = wgid >> 4;    // 0..124
  const int m0 = mt * 256, n0 = nt * 256;

  f32x4 acc[8][4];
#pragma unroll
  for (int m = 0; m < 8; m++)
#pragma unroll
    for (int n = 0; n < 4; n++) acc[m][n] = (f32x4){0.f, 0.f, 0.f, 0.f};

  // per wave 4 gload_lds: A rows w*32+{lq,16+lq}, B rows w*32+{lq,16+lq}
#define STAGE(buf, kk)                                                            \
  do {                                                                            \
    const __hip_bfloat16* gA0 = A + (size_t)(m0 + w * 32 + lq) * K + (kk) + lc * 8;\
    const __hip_bfloat16* gA1 = gA0 + (size_t)16 * K;                             \
    const __hip_bfloat16* gB0 = Bw + (size_t)(n0 + w * 32 + lq) * K + (kk) + lc * 8;\
    const __hip_bfloat16* gB1 = gB0 + (size_t)16 * K;                             \
    __builtin_amdgcn_global_load_lds((const GLOBAL_AS void*)gA0,                  \
        (LDS_AS void*)(&As[buf][w * 1024]), 16, 0, 0);                            \
    __builtin_amdgcn_global_load_lds((const GLOBAL_AS void*)gA1,                  \
        (LDS_AS void*)(&As[buf][w * 1024 + 512]), 16, 0, 0);                      \
    __builtin_amdgcn_global_load_lds((const GLOBAL_AS void*)gB0,                  \
        (LDS_AS void*)(&Bs[buf][w * 1024]), 16, 0, 0);                            \
    __builtin_amdgcn_global_load_lds((const GLOBAL_AS void*)gB1,                  \
        (LDS_AS void*)(&Bs[buf][w * 1024 + 512]), 16, 0, 0);                      \
  } while (0)

  STAGE(0, 0);
  STAGE(1, Kt);

#pragma unroll
  for (int t = 0; t < 8; ++t) {
    if (t < 7) asm volatile("s_waitcnt vmcnt(4)" ::: "memory");  // tile t landed
    else       asm volatile("s_waitcnt vmcnt(0)" ::: "memory");
    __builtin_amdgcn_s_barrier();
    asm volatile("" ::: "memory");

    const int c = t % 3;
    bf16x8 bfr[4];
#pragma unroll
    for (int n = 0; n < 4; n++)
      bfr[n] = *(const bf16x8*)(const void*)(&Bs[c][(wc * 64 + n * 16 + lr) * Kt + lk * 8]);

    if (t < 6) STAGE((t + 2) % 3, (t + 2) * Kt);

    // swapped operands: lane (lr,lk) holds C[m*16+lr][n*16+lk*4 + j], j=0..3
#pragma unroll
    for (int m = 0; m < 8; m++) {
      bf16x8 af = *(const bf16x8*)(const void*)(&As[c][(wr * 128 + m * 16 + lr) * Kt + lk * 8]);
#pragma unroll
      for (int n = 0; n < 4; n++)
        acc[m][n] = __builtin_amdgcn_mfma_f32_16x16x32_bf16(bfr[n], af, acc[m][n], 0, 0, 0);
    }
  }
#undef STAGE

  // bias per thread: 4 n-chunks, constant across m/quarters
  float4 bo_n[4];
#pragma unroll
  for (int n = 0; n < 4; n++)
    bo_n[n] = *(const float4*)(b_out + n0 + wc * 64 + n * 16 + lk * 4);

  // ------------- epilogue: 4 quarter-tiles of 64 rows through LDS ----------
  __syncthreads();  // staging LDS reads fully drained before reuse as tr
#pragma unroll
  for (int q = 0; q < 4; ++q) {
    if (wr == (q >> 1)) {
      const int mbase = (q & 1) * 4;
#pragma unroll
      for (int mm = 0; mm < 4; mm++) {
        const int m = mbase + mm;
        const int row = mm * 16 + lr;  // 0..63 within quarter
#pragma unroll
        for (int n = 0; n < 4; n++) {
          const int col = wc * 64 + n * 16 + lk * 4;
          f32x4 v;
          v[0] = acc[m][n][0] + bo_n[n].x;
          v[1] = acc[m][n][1] + bo_n[n].y;
          v[2] = acc[m][n][2] + bo_n[n].z;
          v[3] = acc[m][n][3] + bo_n[n].w;
          *(f32x4*)&tr[row * 260 + col] = v;
        }
      }
    }
    __syncthreads();
    // all 512 threads stream out 64 rows x 1KB contiguous runs
#pragma unroll
    for (int i = 0; i < 8; ++i) {
      const int c2 = i * 512 + tid;      // 0..4095
      const int row = c2 >> 6;           // 0..63
      const int off = (c2 & 63) * 4;     // 0..252 floats
      f32x4 v = *(const f32x4*)&tr[row * 260 + off];
      __builtin_nontemporal_store(
          v, (f32x4*)(C + (size_t)(m0 + q * 64 + row) * N + n0 + off));
    }
    __syncthreads();
  }
}

// ---------------------------------------------------------------------------
extern "C" void kernel_launch(void* const* d_in, const int* in_sizes, int n_in,
                              void* d_out, int out_size, void* d_ws, size_t ws_size,
                              hipStream_t stream) {
  const int* seq = (const int*)d_in[0];
  const float* hs = (const float*)d_in[1];
  const float* h0 = (const float*)d_in[2];
  const float* emb = (const float*)d_in[3];
  const float* w_ih = (const float*)d_in[4];
  const float* w_hh = (const float*)d_in[5];
  const float* b_ih = (const float*)d_in[6];
  const float* b_hh = (const float*)d_in[7];
  const float* w_out = (const float*)d_in[8];
  const float* b_out = (const float*)d_in[9];

  float* out = (float*)d_out;
  float* logits = out;                          // 131,072,000 f32
  float* state = out + 131072000;               // 4,096 f32
  float* attw = out + 131072000 + 4096;         // 524,288 f32

  char* ws = (char*)d_ws;
  float* xg = (float*)ws;                              // 6,291,456 B
  __hip_bfloat16* cat_bf = (__hip_bfloat16*)(ws + 10485760);   // 2,097,152 B
  __hip_bfloat16* wout_bf = (__hip_bfloat16*)(ws + 12582912);  // 16,384,000 B

  k_embed_proj<<<256, 128, 0, stream>>>(seq, emb, w_ih, b_ih, xg);
  k_gru_attn_cvt<<<532, 512, 0, stream>>>(xg, h0, w_hh, b_hh, hs, cat_bf,
                                          state, attw, w_out, wout_bf);
  k_gemm_mfma<<<2000, 512, 0, stream>>>(cat_bf, wout_bf, b_out, logits);
}

// Round 8
// 251.704 us; speedup vs baseline: 1.2214x; 1.2214x over previous
//
#include <hip/hip_runtime.h>
#include <hip/hip_bf16.h>

#define B_    32
#define SDEC  128
#define SENC  128
#define V_    32000
#define E_    200
#define H_    128
#define G3    384   // 3*H

typedef __attribute__((ext_vector_type(8))) short bf16x8;
typedef __attribute__((ext_vector_type(4))) float f32x4;
typedef __attribute__((ext_vector_type(2))) float f32x2;

#define GLOBAL_AS __attribute__((address_space(1)))
#define LDS_AS    __attribute__((address_space(3)))

__device__ __forceinline__ float fast_sigmoid(float x) {
  return 1.f / (1.f + __expf(-x));
}
__device__ __forceinline__ float fast_tanh(float x) {
  float e2 = __expf(2.f * x);
  return 1.f - 2.f / (e2 + 1.f);
}
// butterfly sum over each aligned 4-lane quad, pure VALU (DPP quad_perm)
__device__ __forceinline__ float quad_reduce(float x) {
  int i = __builtin_bit_cast(int, x);
  int a = __builtin_amdgcn_mov_dpp(i, 0xB1, 0xF, 0xF, true);  // xor 1
  float s = x + __builtin_bit_cast(float, a);
  int j = __builtin_bit_cast(int, s);
  int c = __builtin_amdgcn_mov_dpp(j, 0x4E, 0xF, 0xF, true);  // xor 2
  return s + __builtin_bit_cast(float, c);
}

// ---------------------------------------------------------------------------
// Kernel 1: x = emb[seq]; xg = x @ w_ih^T + b_ih   -> xg [4096][384] f32
// (192-thread 2-col version — the proven R6 shape)
// ---------------------------------------------------------------------------
__global__ __launch_bounds__(192) void k_embed_proj(
    const int* __restrict__ seq, const float* __restrict__ emb,
    const float* __restrict__ w_ih, const float* __restrict__ b_ih,
    float* __restrict__ xg) {
  __shared__ __align__(16) float xs[16][E_];
  __shared__ int sidx[16];
  const int r0 = blockIdx.x * 16;
  const int t = threadIdx.x;
  if (t < 16) sidx[t] = seq[r0 + t];
  __syncthreads();
  for (int i = t; i < 800; i += 192) {
    int r = i / 50, c = i - r * 50;
    *(float4*)&xs[r][c * 4] =
        *(const float4*)(emb + (size_t)sidx[r] * E_ + c * 4);
  }
  __syncthreads();
  const int g0 = t, g1 = t + 192;
  float a0[16], a1[16];
#pragma unroll
  for (int r = 0; r < 16; r++) { a0[r] = 0.f; a1[r] = 0.f; }
  const float* w0 = w_ih + (size_t)g0 * E_;
  const float* w1 = w_ih + (size_t)g1 * E_;
  for (int k = 0; k < E_; k += 4) {
    float4 wv0 = *(const float4*)(w0 + k);
    float4 wv1 = *(const float4*)(w1 + k);
#pragma unroll
    for (int r = 0; r < 16; r++) {
      float4 xv = *(const float4*)&xs[r][k];
      a0[r] += wv0.x * xv.x + wv0.y * xv.y + wv0.z * xv.z + wv0.w * xv.w;
      a1[r] += wv1.x * xv.x + wv1.y * xv.y + wv1.z * xv.z + wv1.w * xv.w;
    }
  }
  const float b0 = b_ih[g0], b1 = b_ih[g1];
#pragma unroll
  for (int r = 0; r < 16; r++) {
    xg[(size_t)(r0 + r) * G3 + g0] = a0[r] + b0;
    xg[(size_t)(r0 + r) * G3 + g1] = a1[r] + b1;
  }
}

// ---------------------------------------------------------------------------
// Kernel 2: blocks 0..31  : GRU scan + fused MFMA attention (one batch each)
//           blocks 32..531: w_out f32->bf16, 4 ILP chunks each
// ---------------------------------------------------------------------------
__global__ __launch_bounds__(512) void k_gru_attn_cvt(
    const float* __restrict__ xg, const float* __restrict__ h0,
    const float* __restrict__ w_hh, const float* __restrict__ b_hh,
    const float* __restrict__ hs, __hip_bfloat16* __restrict__ cat_bf,
    float* __restrict__ state_out, float* __restrict__ attw_out,
    const float* __restrict__ w_out, __hip_bfloat16* __restrict__ wout_bf) {
  if (blockIdx.x >= 32) {
    const int base = (blockIdx.x - 32) * 4;
#pragma unroll
    for (int j = 0; j < 4; j++) {
      int idx = ((base + j) * 512 + threadIdx.x) * 8;
      float4 a = *(const float4*)(w_out + idx);
      float4 c = *(const float4*)(w_out + idx + 4);
      union { __hip_bfloat16 h[8]; uint4 v; } p;
      p.h[0] = __float2bfloat16(a.x); p.h[1] = __float2bfloat16(a.y);
      p.h[2] = __float2bfloat16(a.z); p.h[3] = __float2bfloat16(a.w);
      p.h[4] = __float2bfloat16(c.x); p.h[5] = __float2bfloat16(c.y);
      p.h[6] = __float2bfloat16(c.z); p.h[7] = __float2bfloat16(c.w);
      *(uint4*)(wout_bf + idx) = p.v;
    }
    return;
  }

  __shared__ __hip_bfloat16 ctb[128][128];  // GRU out (scan) -> P (phase 4)
  __shared__ __hip_bfloat16 hsb[128][128];  // hs rows,  chunk c ^ (e&7)
  __shared__ __hip_bfloat16 hsT[128][128];  // hs^T, col' = (e + 8*(h&15))&127
  __shared__ __align__(16) float hp[2][H_];

  const int b = blockIdx.x;
  const int t = threadIdx.x;
  const int hh = t >> 2;   // owned h element
  const int sub = t & 3;   // k-quarter

  float wr_[32], wz_[32], wn_[32];
#pragma unroll
  for (int m = 0; m < 8; m++) {
    int c = (m + sub * 2) & 7;
    int kb = sub * 32 + c * 4;
    *(float4*)&wr_[m * 4] = *(const float4*)(w_hh + (size_t)hh * H_ + kb);
    *(float4*)&wz_[m * 4] = *(const float4*)(w_hh + (size_t)(128 + hh) * H_ + kb);
    *(float4*)&wn_[m * 4] = *(const float4*)(w_hh + (size_t)(256 + hh) * H_ + kb);
  }

  const float* xgb = xg + (size_t)b * SDEC * G3;
  const float br = b_hh[hh], bz = b_hh[128 + hh], bn = b_hh[256 + hh];
  float cxr = xgb[hh], cxz = xgb[128 + hh], cxn = xgb[256 + hh];
  if (t < H_) hp[0][t] = h0[b * H_ + t];
  __hip_bfloat16* catbfb = cat_bf + (size_t)b * SDEC * 256;

  asm volatile("s_waitcnt lgkmcnt(0)" ::: "memory");
  __builtin_amdgcn_s_barrier();
  asm volatile("" ::: "memory");

  int cur = 0;
  for (int s = 0; s < SDEC; s++) {
    float nxr = 0.f, nxz = 0.f, nxn = 0.f;
    if (s + 1 < SDEC) {
      const float* xp = xgb + (size_t)(s + 1) * G3;
      nxr = xp[hh]; nxz = xp[128 + hh]; nxn = xp[256 + hh];
    }
    f32x2 sr2 = {0.f, 0.f}, sz2 = {0.f, 0.f}, sn2 = {0.f, 0.f};
#pragma unroll
    for (int m = 0; m < 8; m++) {
      int c = (m + sub * 2) & 7;
      float4 hv = *(const float4*)&hp[cur][sub * 32 + c * 4];
      f32x2 h01 = {hv.x, hv.y}, h23 = {hv.z, hv.w};
      const f32x2* w2r = (const f32x2*)&wr_[m * 4];
      const f32x2* w2z = (const f32x2*)&wz_[m * 4];
      const f32x2* w2n = (const f32x2*)&wn_[m * 4];
      sr2 += w2r[0] * h01; sr2 += w2r[1] * h23;
      sz2 += w2z[0] * h01; sz2 += w2z[1] * h23;
      sn2 += w2n[0] * h01; sn2 += w2n[1] * h23;
    }
    float sr = quad_reduce(sr2[0] + sr2[1]);
    float sz = quad_reduce(sz2[0] + sz2[1]);
    float sn = quad_reduce(sn2[0] + sn2[1]);

    float hold = hp[cur][hh];
    float r = fast_sigmoid(cxr + sr + br);
    float z = fast_sigmoid(cxz + sz + bz);
    float n = fast_tanh(cxn + r * (sn + bn));
    float hnew = (1.f - z) * n + z * hold;
    if (sub == 0) {
      __hip_bfloat16 hb = __float2bfloat16(hnew);
      hp[cur ^ 1][hh] = hnew;
      catbfb[(size_t)s * 256 + hh] = hb;
      ctb[s][((hh >> 3) ^ (s & 7)) * 8 + (hh & 7)] = hb;  // fragment layout
    }
    asm volatile("s_waitcnt lgkmcnt(0)" ::: "memory");
    __builtin_amdgcn_s_barrier();
    asm volatile("" ::: "memory");
    cur ^= 1;
    cxr = nxr; cxz = nxz; cxn = nxn;
  }

  // ================== fused attention (same block, batch b) ================
  const int w = t >> 6, l = t & 63;
  const int lr = l & 15, lk = l >> 4;
  const float* hsbase = hs + (size_t)b * SENC * H_;

  // stage hs (f32 -> bf16, swizzled rows) + final state
  for (int i = t; i < 2048; i += 512) {
    int e = i >> 4, c = i & 15;
    float4 v0 = *(const float4*)(hsbase + e * H_ + c * 8);
    float4 v1 = *(const float4*)(hsbase + e * H_ + c * 8 + 4);
    union { __hip_bfloat16 h[8]; uint4 u; } pk;
    pk.h[0] = __float2bfloat16(v0.x); pk.h[1] = __float2bfloat16(v0.y);
    pk.h[2] = __float2bfloat16(v0.z); pk.h[3] = __float2bfloat16(v0.w);
    pk.h[4] = __float2bfloat16(v1.x); pk.h[5] = __float2bfloat16(v1.y);
    pk.h[6] = __float2bfloat16(v1.z); pk.h[7] = __float2bfloat16(v1.w);
    *(uint4*)&hsb[e][((c ^ (e & 7)) * 8)] = pk.u;
  }
  if (t < H_) state_out[b * H_ + t] = hp[cur][t];
  __syncthreads();

  // build rotated hs^T from hsb
  for (int i = t; i < 2048; i += 512) {
    int c = i >> 7, e = i & 127;
    uint4 v = *(const uint4*)&hsb[e][((c ^ (e & 7)) * 8)];
    const __hip_bfloat16* hv = (const __hip_bfloat16*)&v;
#pragma unroll
    for (int u = 0; u < 8; u++) {
      int h = c * 8 + u;
      int col = (e + 8 * (h & 15)) & 127;
      hsT[h][col] = hv[u];
    }
  }
  // A-fragments (ct rows) into registers before ctb is overlaid by P
  const int d = w * 16 + lr;
  bf16x8 afrag[4];
#pragma unroll
  for (int kt = 0; kt < 4; kt++)
    afrag[kt] = *(const bf16x8*)&ctb[d][(((kt * 4 + lk) ^ (lr & 7)) * 8)];
  __syncthreads();  // hsT ready; all ctb reads complete

  // phase 2: scores S[d][e]
  f32x4 acc[8];
#pragma unroll
  for (int et = 0; et < 8; et++) acc[et] = (f32x4){0.f, 0.f, 0.f, 0.f};
  __builtin_amdgcn_s_setprio(1);
#pragma unroll
  for (int et = 0; et < 8; et++) {
#pragma unroll
    for (int kt = 0; kt < 4; kt++) {
      bf16x8 bfrag =
          *(const bf16x8*)&hsb[et * 16 + lr][(((kt * 4 + lk) ^ (lr & 7)) * 8)];
      acc[et] =
          __builtin_amdgcn_mfma_f32_16x16x32_bf16(bfrag, afrag[kt], acc[et], 0, 0, 0);
    }
  }
  __builtin_amdgcn_s_setprio(0);

  // phase 3: softmax over e, in-register
  float mx = -1e30f;
#pragma unroll
  for (int et = 0; et < 8; et++)
    mx = fmaxf(mx, fmaxf(fmaxf(acc[et][0], acc[et][1]),
                         fmaxf(acc[et][2], acc[et][3])));
  mx = fmaxf(mx, __shfl_xor(mx, 16));
  mx = fmaxf(mx, __shfl_xor(mx, 32));
  float sum = 0.f;
#pragma unroll
  for (int et = 0; et < 8; et++) {
    acc[et][0] = __expf(acc[et][0] - mx);
    acc[et][1] = __expf(acc[et][1] - mx);
    acc[et][2] = __expf(acc[et][2] - mx);
    acc[et][3] = __expf(acc[et][3] - mx);
    sum += acc[et][0] + acc[et][1] + acc[et][2] + acc[et][3];
  }
  sum += __shfl_xor(sum, 16);
  sum += __shfl_xor(sum, 32);
  const float inv = 1.f / sum;

  // write P (bf16, into ctb space) + attw (f32)
  __hip_bfloat16 (*plds)[128] = ctb;
  float* aw = attw_out + (size_t)b * SENC * SDEC + d;
#pragma unroll
  for (int et = 0; et < 8; et++) {
    acc[et][0] *= inv; acc[et][1] *= inv;
    acc[et][2] *= inv; acc[et][3] *= inv;
    union { __hip_bfloat16 h[4]; uint2 u; } pk4;
    pk4.h[0] = __float2bfloat16(acc[et][0]);
    pk4.h[1] = __float2bfloat16(acc[et][1]);
    pk4.h[2] = __float2bfloat16(acc[et][2]);
    pk4.h[3] = __float2bfloat16(acc[et][3]);
    *(uint2*)&plds[d][(((et * 2 + (lk >> 1)) ^ (lr & 7)) * 8 + 4 * (lk & 1))] =
        pk4.u;
    const int e0 = et * 16 + lk * 4;
#pragma unroll
    for (int j = 0; j < 4; j++)
      aw[(size_t)(e0 + j) * SDEC] = acc[et][j];
  }
  __syncthreads();

  // phase 4: context c[d][h] = P @ hs
  bf16x8 pfrag[4];
#pragma unroll
  for (int f = 0; f < 4; f++)
    pfrag[f] = *(const bf16x8*)&plds[d][(((f * 4 + lk) ^ (lr & 7)) * 8)];
#pragma unroll
  for (int ht = 0; ht < 8; ht++) {
    f32x4 a2 = (f32x4){0.f, 0.f, 0.f, 0.f};
    __builtin_amdgcn_s_setprio(1);
#pragma unroll
    for (int kt = 0; kt < 4; kt++) {
      bf16x8 hfrag =
          *(const bf16x8*)&hsT[ht * 16 + lr][((kt * 32 + lk * 8 + 8 * lr) & 127)];
      a2 = __builtin_amdgcn_mfma_f32_16x16x32_bf16(hfrag, pfrag[kt], a2, 0, 0, 0);
    }
    __builtin_amdgcn_s_setprio(0);
    union { __hip_bfloat16 h[4]; uint2 u; } pk4;
    pk4.h[0] = __float2bfloat16(a2[0]);
    pk4.h[1] = __float2bfloat16(a2[1]);
    pk4.h[2] = __float2bfloat16(a2[2]);
    pk4.h[3] = __float2bfloat16(a2[3]);
    *(uint2*)(cat_bf + (size_t)(b * SDEC + d) * 256 + 128 + ht * 16 + lk * 4) =
        pk4.u;
  }
}

// ---------------------------------------------------------------------------
// Kernel 4: logits = cat @ w_out^T + b_out  (R4 structure verbatim +
// s_setprio(1) around the MFMA cluster — the single variable this round)
// ---------------------------------------------------------------------------
__global__ __launch_bounds__(512) void k_gemm_mfma(
    const __hip_bfloat16* __restrict__ A, const __hip_bfloat16* __restrict__ Bw,
    const float* __restrict__ b_out, float* __restrict__ C) {
  constexpr int K = 256, N = V_, Kt = 32;
  alignas(16) __shared__ char smem[73728];  // 72 KB
  __hip_bfloat16 (*As)[4096] = (__hip_bfloat16(*)[4096])smem;            // [3][128*32]
  __hip_bfloat16 (*Bs)[8192] = (__hip_bfloat16(*)[8192])(smem + 24576);  // [3][256*32]
  float* tr = (float*)smem;  // epilogue: [64][260] padded f32 half-tile

  const int tid = threadIdx.x;
  const int w = tid >> 6, l = tid & 63;
  const int wr = w >> 2, wc = w & 3;       // 2M x 4N waves, each 64x64
  const int lr = l & 15, lk = l >> 4;
  const int lq = l >> 2, lc = l & 3;

  const int bid = blockIdx.x;
  const int wgid = (bid & 7) * 500 + (bid >> 3);
  const int mt = wgid & 31;
  const int nt = wgid >> 5;
  const int m0 = mt * 128, n0 = nt * 256;

  f32x4 acc[4][4];
#pragma unroll
  for (int m = 0; m < 4; m++)
#pragma unroll
    for (int n = 0; n < 4; n++) acc[m][n] = (f32x4){0.f, 0.f, 0.f, 0.f};

#define STAGE(buf, kk)                                                            \
  do {                                                                            \
    const __hip_bfloat16* gA = A + (size_t)(m0 + w * 16 + lq) * K + (kk) + lc * 8;\
    const __hip_bfloat16* gB0 = Bw + (size_t)(n0 + w * 32 + lq) * K + (kk) + lc * 8;\
    const __hip_bfloat16* gB1 = gB0 + (size_t)16 * K;                             \
    __builtin_amdgcn_global_load_lds((const GLOBAL_AS void*)gA,                   \
        (LDS_AS void*)(&As[buf][w * 512]), 16, 0, 0);                             \
    __builtin_amdgcn_global_load_lds((const GLOBAL_AS void*)gB0,                  \
        (LDS_AS void*)(&Bs[buf][w * 1024]), 16, 0, 0);                            \
    __builtin_amdgcn_global_load_lds((const GLOBAL_AS void*)gB1,                  \
        (LDS_AS void*)(&Bs[buf][w * 1024 + 512]), 16, 0, 0);                      \
  } while (0)

  STAGE(0, 0);
  STAGE(1, Kt);

#pragma unroll
  for (int t = 0; t < 8; ++t) {
    if (t < 7) asm volatile("s_waitcnt vmcnt(3)" ::: "memory");
    else       asm volatile("s_waitcnt vmcnt(0)" ::: "memory");
    __builtin_amdgcn_s_barrier();
    asm volatile("" ::: "memory");

    const int c = t % 3;
    bf16x8 af[4], bfr[4];
#pragma unroll
    for (int m = 0; m < 4; m++)
      af[m] = *(const bf16x8*)(const void*)(&As[c][(wr * 64 + m * 16 + lr) * Kt + lk * 8]);
#pragma unroll
    for (int n = 0; n < 4; n++)
      bfr[n] = *(const bf16x8*)(const void*)(&Bs[c][(wc * 64 + n * 16 + lr) * Kt + lk * 8]);

    if (t < 6) STAGE((t + 2) % 3, (t + 2) * Kt);

    __builtin_amdgcn_s_setprio(1);
#pragma unroll
    for (int m = 0; m < 4; m++)
#pragma unroll
      for (int n = 0; n < 4; n++)
        acc[m][n] = __builtin_amdgcn_mfma_f32_16x16x32_bf16(bfr[n], af[m], acc[m][n], 0, 0, 0);
    __builtin_amdgcn_s_setprio(0);
  }
#undef STAGE

  __syncthreads();
#pragma unroll
  for (int h = 0; h < 2; ++h) {
    if (wr == h) {
#pragma unroll
      for (int m = 0; m < 4; m++) {
#pragma unroll
        for (int n = 0; n < 4; n++) {
          const int row = m * 16 + lr;
          const int col = wc * 64 + n * 16 + lk * 4;
          const float4 bo = *(const float4*)(b_out + n0 + col);
          f32x4 v;
          v[0] = acc[m][n][0] + bo.x;
          v[1] = acc[m][n][1] + bo.y;
          v[2] = acc[m][n][2] + bo.z;
          v[3] = acc[m][n][3] + bo.w;
          *(f32x4*)&tr[row * 260 + col] = v;
        }
      }
    }
    __syncthreads();
#pragma unroll
    for (int i = 0; i < 8; ++i) {
      const int c2 = i * 512 + tid;
      const int row = c2 >> 6;
      const int off = (c2 & 63) * 4;
      f32x4 v = *(const f32x4*)&tr[row * 260 + off];
      __builtin_nontemporal_store(
          v, (f32x4*)(C + (size_t)(m0 + h * 64 + row) * N + n0 + off));
    }
    __syncthreads();
  }
}

// ---------------------------------------------------------------------------
extern "C" void kernel_launch(void* const* d_in, const int* in_sizes, int n_in,
                              void* d_out, int out_size, void* d_ws, size_t ws_size,
                              hipStream_t stream) {
  const int* seq = (const int*)d_in[0];
  const float* hs = (const float*)d_in[1];
  const float* h0 = (const float*)d_in[2];
  const float* emb = (const float*)d_in[3];
  const float* w_ih = (const float*)d_in[4];
  const float* w_hh = (const float*)d_in[5];
  const float* b_ih = (const float*)d_in[6];
  const float* b_hh = (const float*)d_in[7];
  const float* w_out = (const float*)d_in[8];
  const float* b_out = (const float*)d_in[9];

  float* out = (float*)d_out;
  float* logits = out;                          // 131,072,000 f32
  float* state = out + 131072000;               // 4,096 f32
  float* attw = out + 131072000 + 4096;         // 524,288 f32

  char* ws = (char*)d_ws;
  float* xg = (float*)ws;                              // 6,291,456 B
  __hip_bfloat16* cat_bf = (__hip_bfloat16*)(ws + 10485760);   // 2,097,152 B
  __hip_bfloat16* wout_bf = (__hip_bfloat16*)(ws + 12582912);  // 16,384,000 B

  k_embed_proj<<<256, 192, 0, stream>>>(seq, emb, w_ih, b_ih, xg);
  k_gru_attn_cvt<<<532, 512, 0, stream>>>(xg, h0, w_hh, b_hh, hs, cat_bf,
                                          state, attw, w_out, wout_bf);
  k_gemm_mfma<<<4000, 512, 0, stream>>>(cat_bf, wout_bf, b_out, logits);
}